// Round 15
// baseline (92.159 us; speedup 1.0000x reference)
//
#include <hip/hip_runtime.h>
#include <hip/hip_bf16.h>

#define DD 512      // feature dim
#define NTOP 10     // topic_e
#define NTK 6       // num_topics
#define NPAIR 60    // NTOP*NTK

typedef float f32x4 __attribute__((ext_vector_type(4)));
typedef short bf16x8 __attribute__((ext_vector_type(8)));
typedef unsigned short us8 __attribute__((ext_vector_type(8)));
typedef unsigned short us4 __attribute__((ext_vector_type(4)));

__device__ __forceinline__ void gload16(const void* g, void* l) {
  __builtin_amdgcn_global_load_lds(
      (const __attribute__((address_space(1))) unsigned int*)g,
      (__attribute__((address_space(3))) unsigned int*)l, 16, 0, 0);
}

// ---------------------------------------------------------------------------
// Kernel 1: per-row argmax (packed nibble code) + inverse norm + col_sum=0.
// ---------------------------------------------------------------------------
__global__ __launch_bounds__(256) void kern_wmax(
    const float* __restrict__ x, const float* __restrict__ H,
    int* __restrict__ codes, float* __restrict__ inv_norm,
    float* __restrict__ col_sum)
{
  __shared__ float xs[4][DD];
  __shared__ float w[4][NPAIR];
  const int wv = threadIdx.x >> 6, lane = threadIdx.x & 63;
  const int n = blockIdx.x * 4 + wv;
  const float* xr = x + (size_t)n * DD;
  float ss = 0.f;
#pragma unroll
  for (int j = 0; j < 2; ++j) {
    float4 v = *(const float4*)(xr + j * 256 + lane * 4);
    *(float4*)&xs[wv][j * 256 + lane * 4] = v;
    ss = fmaf(v.x, v.x, fmaf(v.y, v.y, fmaf(v.z, v.z, fmaf(v.w, v.w, ss))));
  }
#pragma unroll
  for (int off = 32; off; off >>= 1) ss += __shfl_xor(ss, off);
  if (lane == 0) inv_norm[n] = 1.0f / fmaxf(sqrtf(ss), 1e-8f);
  __syncthreads();
  if (lane < NPAIR) {
    float acc = 0.f;
#pragma unroll 8
    for (int d = 0; d < DD; ++d) acc = fmaf(xs[wv][d], H[d * NPAIR + lane], acc);
    w[wv][lane] = acc;
  }
  __syncthreads();
  int myc = 0;
  if (lane < NTK) {
    float best = w[wv][lane];
    int bi = 0;
#pragma unroll
    for (int t = 1; t < NTOP; ++t) {
      float v = w[wv][t * NTK + lane];
      if (v > best) { best = v; bi = t; }  // strict > == jnp.argmax first-index tie rule
    }
    myc = bi << (4 * lane);
  }
#pragma unroll
  for (int off = 1; off <= 4; off <<= 1) myc |= __shfl_xor(myc, off);
  if (lane == 0) { codes[n] = myc; col_sum[n] = 0.f; }
}

// ---------------------------------------------------------------------------
// Kernel 2: xn = bf16(x * inv_norm) row-major; xT = bf16(x)^T  (D x N)
// ---------------------------------------------------------------------------
__global__ __launch_bounds__(256) void kern_prep(
    const float* __restrict__ x, const float* __restrict__ inv_norm,
    __hip_bfloat16* __restrict__ xn, __hip_bfloat16* __restrict__ xT, int N)
{
  __shared__ float tile[64][65];
  const int n0 = blockIdx.x * 64, d0 = blockIdx.y * 64;
  const int tid = threadIdx.x;
  const int r = tid >> 2, cseg = (tid & 3) * 16;
  const float* src = x + (size_t)(n0 + r) * DD + d0 + cseg;
  const float invn = inv_norm[n0 + r];
  unsigned short hb[16];
#pragma unroll
  for (int q = 0; q < 4; ++q) {
    float4 v = *(const float4*)(src + q * 4);
    tile[r][cseg + q * 4 + 0] = v.x; tile[r][cseg + q * 4 + 1] = v.y;
    tile[r][cseg + q * 4 + 2] = v.z; tile[r][cseg + q * 4 + 3] = v.w;
    hb[q * 4 + 0] = __builtin_bit_cast(unsigned short, __float2bfloat16(v.x * invn));
    hb[q * 4 + 1] = __builtin_bit_cast(unsigned short, __float2bfloat16(v.y * invn));
    hb[q * 4 + 2] = __builtin_bit_cast(unsigned short, __float2bfloat16(v.z * invn));
    hb[q * 4 + 3] = __builtin_bit_cast(unsigned short, __float2bfloat16(v.w * invn));
  }
  us8 v0, v1;
#pragma unroll
  for (int i = 0; i < 8; ++i) { v0[i] = hb[i]; v1[i] = hb[i + 8]; }
  *(us8*)(xn + (size_t)(n0 + r) * DD + d0 + cseg) = v0;
  *(us8*)(xn + (size_t)(n0 + r) * DD + d0 + cseg + 8) = v1;
  __syncthreads();
  const int drow = tid >> 2, nseg = (tid & 3) * 16;
  unsigned short hb2[16];
#pragma unroll
  for (int i = 0; i < 16; ++i)
    hb2[i] = __builtin_bit_cast(unsigned short, __float2bfloat16(tile[nseg + i][drow]));
  us8 w0, w1;
#pragma unroll
  for (int i = 0; i < 8; ++i) { w0[i] = hb2[i]; w1[i] = hb2[i + 8]; }
  *(us8*)(xT + (size_t)(d0 + drow) * N + n0 + nseg) = w0;
  *(us8*)(xT + (size_t)(d0 + drow) * N + n0 + nseg + 8) = w1;
}

// ---------------------------------------------------------------------------
// Kernel 3: Gram MFMA, triangular tiles, 512 threads, NOW with the validated
// 2-phase stage-early pipeline (dbuf 64 KB, STAGE(t+1) before compute(t),
// one vmcnt(0)+s_barrier per K-step). Epilogue identical to round 12/14.
// ---------------------------------------------------------------------------
#define GBM 128
#define GBK 64
#define GNT 8   // K-steps: 512/64

__global__ __launch_bounds__(512, 4) void kern_gram(
    const __hip_bfloat16* __restrict__ xn, const int* __restrict__ codes,
    __hip_bfloat16* __restrict__ Cb, float* __restrict__ col_sum, int N)
{
  __shared__ __hip_bfloat16 As[2][GBM * GBK];  // 2 x 16 KB
  __shared__ __hip_bfloat16 Bs[2][GBM * GBK];  // 2 x 16 KB
  __shared__ float csA[GBM], csB[GBM];
  const int tid = threadIdx.x;

  int idx = blockIdx.x, ai = 0, rem = N / GBM;
  while (idx >= rem) { idx -= rem; ++ai; --rem; }
  const int bi = ai + idx;
  const bool diag = (ai == bi);
  const int a0 = ai * GBM, b0 = bi * GBM;

  if (tid < GBM) { csA[tid] = 0.f; csB[tid] = 0.f; }

  const int lane = tid & 63, wid = tid >> 6;
  const int wr = wid >> 2, wc = wid & 3;     // 2 x 4 wave grid

  const f32x4 fz = {0.f, 0.f, 0.f, 0.f};
  f32x4 acc[4][2];
#pragma unroll
  for (int m = 0; m < 4; ++m)
#pragma unroll
    for (int n = 0; n < 2; ++n) acc[m][n] = fz;

  int ldsoff[2]; size_t srcA[2], srcB[2];
#pragma unroll
  for (int i = 0; i < 2; ++i) {
    int p = i * 8192 + tid * 16;
    int row = p >> 7, c = (p >> 4) & 7;
    ldsoff[i] = p;
    size_t cc = (size_t)((c ^ (row & 7)) << 4);
    srcA[i] = (size_t)(a0 + row) * (DD * 2) + cc;
    srcB[i] = (size_t)(b0 + row) * (DD * 2) + cc;
  }
  const char* xc = (const char*)xn;

#define GSTAGE(t, buf) do { \
    const size_t kc = (size_t)(t) * (GBK * 2); \
    _Pragma("unroll") \
    for (int i = 0; i < 2; ++i) { \
      gload16(xc + srcA[i] + kc, (char*)As[buf] + ldsoff[i]); \
      gload16(xc + srcB[i] + kc, (char*)Bs[buf] + ldsoff[i]); \
    } } while (0)

  GSTAGE(0, 0);
  asm volatile("s_waitcnt vmcnt(0)" ::: "memory");
  __builtin_amdgcn_s_barrier();

  for (int t = 0; t < GNT; ++t) {
    const int cur = t & 1;
    if (t + 1 < GNT) GSTAGE(t + 1, cur ^ 1);   // overlap with compute below
    const char* Ab = (const char*)As[cur];
    const char* Bb = (const char*)Bs[cur];
#pragma unroll
    for (int kk = 0; kk < 2; ++kk) {
      const int kb = kk * 64 + (lane >> 4) * 16;
      bf16x8 af[4], bfr[2];
#pragma unroll
      for (int m = 0; m < 4; ++m) {
        int r = wr * 64 + m * 16 + (lane & 15);
        af[m] = *(const bf16x8*)(Ab + r * 128 + (kb ^ ((r & 7) << 4)));
      }
#pragma unroll
      for (int n = 0; n < 2; ++n) {
        int r = wc * 32 + n * 16 + (lane & 15);
        bfr[n] = *(const bf16x8*)(Bb + r * 128 + (kb ^ ((r & 7) << 4)));
      }
#pragma unroll
      for (int m = 0; m < 4; ++m)
#pragma unroll
        for (int n = 0; n < 2; ++n)
          acc[m][n] = __builtin_amdgcn_mfma_f32_16x16x32_bf16(af[m], bfr[n], acc[m][n], 0, 0, 0);
    }
    asm volatile("s_waitcnt vmcnt(0)" ::: "memory");
    __builtin_amdgcn_s_barrier();
  }
#undef GSTAGE

  // ---- epilogue (identical to round 12/14) ----
  char* ldsb = (char*)As;    // staging: [128 rows][256 B], chunk-XOR swizzled
  const int rq = (lane >> 4) << 2;
  int cb[2];
#pragma unroll
  for (int n = 0; n < 2; ++n) cb[n] = codes[b0 + wc * 32 + n * 16 + (lane & 15)];

  us4 tvs[4][2];             // keep bf16 fragments for the transpose pass
  float colpart[2] = {0.f, 0.f};
  float rowpart[4][4] = {};
#pragma unroll
  for (int m = 0; m < 4; ++m) {
    int ca[4];
#pragma unroll
    for (int j = 0; j < 4; ++j) ca[j] = codes[a0 + wr * 64 + m * 16 + rq + j];
#pragma unroll
    for (int n = 0; n < 2; ++n) {
      const int col = wc * 32 + n * 16 + (lane & 15);
#pragma unroll
      for (int j = 0; j < 4; ++j) {
        int t = ca[j] ^ cb[n];
        t |= t >> 1; t |= t >> 2;
        t &= 0x111111;
        float f = (float)(6 - __popc(t)) * (1.0f / 6.0f);
        float cv = acc[m][n][j] * f;
        colpart[n] += cv;
        rowpart[m][j] += cv;
        __hip_bfloat16 hv = __float2bfloat16(cv);
        tvs[m][n][j] = __builtin_bit_cast(unsigned short, hv);
        const int row = wr * 64 + m * 16 + rq + j;
        const int boff = row * 256 + ((((col >> 3) ^ (row & 7)) << 4) | ((col & 7) << 1));
        *(__hip_bfloat16*)(ldsb + boff) = hv;
      }
    }
  }
#pragma unroll
  for (int n = 0; n < 2; ++n) {
    float v = colpart[n];
    v += __shfl_xor(v, 16);
    v += __shfl_xor(v, 32);
    if (lane < 16) atomicAdd(&csB[wc * 32 + n * 16 + lane], v);
  }
  if (!diag) {
#pragma unroll
    for (int m = 0; m < 4; ++m)
#pragma unroll
      for (int j = 0; j < 4; ++j) {
        float v = rowpart[m][j];
        v += __shfl_xor(v, 1);
        v += __shfl_xor(v, 2);
        v += __shfl_xor(v, 4);
        v += __shfl_xor(v, 8);
        if ((lane & 15) == 0)
          atomicAdd(&csA[wr * 64 + m * 16 + rq + j], v);
      }
  }
  __syncthreads();
  // pass A copy-out: 512 threads, 4 iters cover 128 rows x 256 B
#pragma unroll
  for (int i = 0; i < 4; ++i) {
    const int row = i * 32 + (tid >> 4);
    const int ch = tid & 15;
    us8 v = *(us8*)(ldsb + row * 256 + ((ch ^ (row & 7)) << 4));
    *(us8*)((char*)Cb + ((size_t)(a0 + row) * N + b0) * 2 + (ch << 4)) = v;
  }
  if (!diag) {
    __syncthreads();
#pragma unroll
    for (int m = 0; m < 4; ++m) {
      const int row0 = wr * 64 + m * 16 + rq;
      const int chT = row0 >> 3;
      const int byo = (row0 & 7) << 1;
#pragma unroll
      for (int n = 0; n < 2; ++n) {
        const int col = wc * 32 + n * 16 + (lane & 15);
        *(us4*)(ldsb + col * 256 + (((chT ^ (col & 7)) << 4) | byo)) = tvs[m][n];
      }
    }
    __syncthreads();
#pragma unroll
    for (int i = 0; i < 4; ++i) {
      const int row = i * 32 + (tid >> 4);
      const int ch = tid & 15;
      us8 v = *(us8*)(ldsb + row * 256 + ((ch ^ (row & 7)) << 4));
      *(us8*)((char*)Cb + ((size_t)(b0 + row) * N + a0) * 2 + (ch << 4)) = v;
    }
  }
  if (tid < GBM) {
    atomicAdd(&col_sum[b0 + tid], csB[tid]);
    if (!diag) atomicAdd(&col_sum[a0 + tid], csA[tid]);
  }
}

// ---------------------------------------------------------------------------
// Kernel 4: out2 partials (round-14, unchanged): 128x128, OSK=4, 512 threads,
// 2-phase stage-early dbuf pipeline, plain f32 partial stores.
// ---------------------------------------------------------------------------
#define OM 128
#define ON 128
#define OK 64
#define OSK 4
#define ONT 16   // K-steps: (4096/4)/64

__global__ __launch_bounds__(512, 4) void kern_out2(
    const __hip_bfloat16* __restrict__ Cb, const __hip_bfloat16* __restrict__ xT,
    float* __restrict__ part, int N)
{
  __shared__ __hip_bfloat16 As[2][OM * OK];   // 2 x 16 KB
  __shared__ __hip_bfloat16 Bs[2][ON * OK];   // 2 x 16 KB
  const int tid = threadIdx.x;
  const int b0 = blockIdx.x * OM;
  const int d0 = blockIdx.y * ON;
  const size_t kbyte0 = (size_t)blockIdx.z * (N / OSK) * 2;
  const int lane = tid & 63, wid = tid >> 6;
  const int wr = wid >> 2, wc = wid & 3;   // 2 x 4 wave grid

  const f32x4 fz = {0.f, 0.f, 0.f, 0.f};
  f32x4 acc[4][2];
#pragma unroll
  for (int m = 0; m < 4; ++m)
#pragma unroll
    for (int n = 0; n < 2; ++n) acc[m][n] = fz;

  int ldso[2]; size_t srcA[2], srcB[2];
#pragma unroll
  for (int i = 0; i < 2; ++i) {
    int p = i * 8192 + tid * 16;
    int row = p >> 7, c = (p >> 4) & 7;
    ldso[i] = p;
    size_t cc = (size_t)((c ^ (row & 7)) << 4);
    srcA[i] = (size_t)(b0 + row) * ((size_t)N * 2) + cc + kbyte0;
    srcB[i] = (size_t)(d0 + row) * ((size_t)N * 2) + cc + kbyte0;
  }
  const char* Ac = (const char*)Cb;
  const char* Bc = (const char*)xT;

#define OSTAGE(t, buf) do { \
    const size_t kc = (size_t)(t) * (OK * 2); \
    _Pragma("unroll") \
    for (int i = 0; i < 2; ++i) { \
      gload16(Ac + srcA[i] + kc, (char*)As[buf] + ldso[i]); \
      gload16(Bc + srcB[i] + kc, (char*)Bs[buf] + ldso[i]); \
    } } while (0)

  OSTAGE(0, 0);
  asm volatile("s_waitcnt vmcnt(0)" ::: "memory");
  __builtin_amdgcn_s_barrier();

  for (int t = 0; t < ONT; ++t) {
    const int cur = t & 1;
    if (t + 1 < ONT) OSTAGE(t + 1, cur ^ 1);   // overlap with compute below
    const char* Ab = (const char*)As[cur];
    const char* Bb = (const char*)Bs[cur];
#pragma unroll
    for (int kk = 0; kk < 2; ++kk) {
      const int kb = kk * 64 + (lane >> 4) * 16;
      bf16x8 af[4], bfr[2];
#pragma unroll
      for (int m = 0; m < 4; ++m) {
        int r = wr * 64 + m * 16 + (lane & 15);
        af[m] = *(const bf16x8*)(Ab + r * 128 + (kb ^ ((r & 7) << 4)));
      }
#pragma unroll
      for (int n = 0; n < 2; ++n) {
        int r = wc * 32 + n * 16 + (lane & 15);
        bfr[n] = *(const bf16x8*)(Bb + r * 128 + (kb ^ ((r & 7) << 4)));
      }
#pragma unroll
      for (int m = 0; m < 4; ++m)
#pragma unroll
        for (int n = 0; n < 2; ++n)
          acc[m][n] = __builtin_amdgcn_mfma_f32_16x16x32_bf16(af[m], bfr[n], acc[m][n], 0, 0, 0);
    }
    asm volatile("s_waitcnt vmcnt(0)" ::: "memory");
    __builtin_amdgcn_s_barrier();
  }
#undef OSTAGE

  float* pz = part + (size_t)blockIdx.z * N * DD;
#pragma unroll
  for (int m = 0; m < 4; ++m)
#pragma unroll
    for (int j = 0; j < 4; ++j) {
      int b = b0 + wr * 64 + m * 16 + ((lane >> 4) << 2) + j;
#pragma unroll
      for (int n = 0; n < 2; ++n) {
        int d = d0 + wc * 32 + n * 16 + (lane & 15);
        pz[(size_t)b * DD + d] = acc[m][n][j];
      }
    }
}

// ---------------------------------------------------------------------------
// Kernel 5: finish. One block per row n; sums `osk` partial slices.
// ---------------------------------------------------------------------------
__global__ __launch_bounds__(256) void kern_finish(
    const float* __restrict__ x, const float* __restrict__ col_sum,
    const float* __restrict__ part, float* __restrict__ out, int N, int osk)
{
  const int n = blockIdx.x;
  const int tid = threadIdx.x;
  const float invN = 1.0f / (float)N;
  if (tid < 128) {
    const float s = col_sum[n] * invN;
    float4 v = ((const float4*)(x + (size_t)n * DD))[tid];
    v.x *= s; v.y *= s; v.z *= s; v.w *= s;
    ((float4*)(out + (size_t)n * (2 * DD)))[tid] = v;
  } else {
    const int d4 = tid - 128;
    const size_t stride = (size_t)N * DD;
    float4 r = {0.f, 0.f, 0.f, 0.f};
    for (int z = 0; z < osk; ++z) {
      float4 p = *((const float4*)(part + (size_t)z * stride + (size_t)n * DD) + d4);
      r.x += p.x; r.y += p.y; r.z += p.z; r.w += p.w;
    }
    r.x *= invN; r.y *= invN; r.z *= invN; r.w *= invN;
    ((float4*)(out + (size_t)n * (2 * DD) + DD))[d4] = r;
  }
}

extern "C" void kernel_launch(void* const* d_in, const int* in_sizes, int n_in,
                              void* d_out, int out_size, void* d_ws, size_t ws_size,
                              hipStream_t stream) {
  const float* x = (const float*)d_in[0];
  const float* H = (const float*)d_in[1];
  float* out = (float*)d_out;
  const int N = in_sizes[0] / DD;  // 4096

  char* ws = (char*)d_ws;
  __hip_bfloat16* Cb   = (__hip_bfloat16*)ws;                       // N*N bf16 (32 MB)
  __hip_bfloat16* xn16 = (__hip_bfloat16*)(ws + (size_t)N * N * 2); // N*DD bf16 (4 MB)
  __hip_bfloat16* xT16 = xn16 + (size_t)N * DD;                     // DD*N bf16 (4 MB)
  float* col_sum  = (float*)(xT16 + (size_t)N * DD);                // N f32
  float* inv_norm = col_sum + N;                                    // N f32
  int*   codes    = (int*)(inv_norm + N);                           // N int
  float* part     = (float*)(codes + N);                            // OSK*N*DD f32

  kern_wmax<<<N / 4, 256, 0, stream>>>(x, H, codes, inv_norm, col_sum);
  kern_prep<<<dim3(N / 64, DD / 64), 256, 0, stream>>>(x, inv_norm, xn16, xT16, N);
  const int T = N / GBM;
  kern_gram<<<T * (T + 1) / 2, 512, 0, stream>>>(xn16, codes, Cb, col_sum, N);
  kern_out2<<<dim3(N / OM, DD / ON, OSK), 512, 0, stream>>>(Cb, xT16, part, N);
  kern_finish<<<N, 256, 0, stream>>>(x, col_sum, part, out, N, OSK);
}

// Round 16
// 83.345 us; speedup vs baseline: 1.1058x; 1.1058x over previous
//
#include <hip/hip_runtime.h>
#include <hip/hip_bf16.h>

#define DD 512      // feature dim
#define NTOP 10     // topic_e
#define NTK 6       // num_topics
#define NPAIR 60    // NTOP*NTK

typedef float f32x4 __attribute__((ext_vector_type(4)));
typedef short bf16x8 __attribute__((ext_vector_type(8)));
typedef unsigned short us8 __attribute__((ext_vector_type(8)));
typedef unsigned short us4 __attribute__((ext_vector_type(4)));

__device__ __forceinline__ void gload16(const void* g, void* l) {
  __builtin_amdgcn_global_load_lds(
      (const __attribute__((address_space(1))) unsigned int*)g,
      (__attribute__((address_space(3))) unsigned int*)l, 16, 0, 0);
}

// ---------------------------------------------------------------------------
// Kernel 1: per-row argmax (packed nibble code) + inverse norm + col_sum=0.
// ---------------------------------------------------------------------------
__global__ __launch_bounds__(256) void kern_wmax(
    const float* __restrict__ x, const float* __restrict__ H,
    int* __restrict__ codes, float* __restrict__ inv_norm,
    float* __restrict__ col_sum)
{
  __shared__ float xs[4][DD];
  __shared__ float w[4][NPAIR];
  const int wv = threadIdx.x >> 6, lane = threadIdx.x & 63;
  const int n = blockIdx.x * 4 + wv;
  const float* xr = x + (size_t)n * DD;
  float ss = 0.f;
#pragma unroll
  for (int j = 0; j < 2; ++j) {
    float4 v = *(const float4*)(xr + j * 256 + lane * 4);
    *(float4*)&xs[wv][j * 256 + lane * 4] = v;
    ss = fmaf(v.x, v.x, fmaf(v.y, v.y, fmaf(v.z, v.z, fmaf(v.w, v.w, ss))));
  }
#pragma unroll
  for (int off = 32; off; off >>= 1) ss += __shfl_xor(ss, off);
  if (lane == 0) inv_norm[n] = 1.0f / fmaxf(sqrtf(ss), 1e-8f);
  __syncthreads();
  if (lane < NPAIR) {
    float acc = 0.f;
#pragma unroll 8
    for (int d = 0; d < DD; ++d) acc = fmaf(xs[wv][d], H[d * NPAIR + lane], acc);
    w[wv][lane] = acc;
  }
  __syncthreads();
  int myc = 0;
  if (lane < NTK) {
    float best = w[wv][lane];
    int bi = 0;
#pragma unroll
    for (int t = 1; t < NTOP; ++t) {
      float v = w[wv][t * NTK + lane];
      if (v > best) { best = v; bi = t; }  // strict > == jnp.argmax first-index tie rule
    }
    myc = bi << (4 * lane);
  }
#pragma unroll
  for (int off = 1; off <= 4; off <<= 1) myc |= __shfl_xor(myc, off);
  if (lane == 0) { codes[n] = myc; col_sum[n] = 0.f; }
}

// ---------------------------------------------------------------------------
// Kernel 2: xn = bf16(x * inv_norm) row-major; xT = bf16(x)^T  (D x N)
// ---------------------------------------------------------------------------
__global__ __launch_bounds__(256) void kern_prep(
    const float* __restrict__ x, const float* __restrict__ inv_norm,
    __hip_bfloat16* __restrict__ xn, __hip_bfloat16* __restrict__ xT, int N)
{
  __shared__ float tile[64][65];
  const int n0 = blockIdx.x * 64, d0 = blockIdx.y * 64;
  const int tid = threadIdx.x;
  const int r = tid >> 2, cseg = (tid & 3) * 16;
  const float* src = x + (size_t)(n0 + r) * DD + d0 + cseg;
  const float invn = inv_norm[n0 + r];
  unsigned short hb[16];
#pragma unroll
  for (int q = 0; q < 4; ++q) {
    float4 v = *(const float4*)(src + q * 4);
    tile[r][cseg + q * 4 + 0] = v.x; tile[r][cseg + q * 4 + 1] = v.y;
    tile[r][cseg + q * 4 + 2] = v.z; tile[r][cseg + q * 4 + 3] = v.w;
    hb[q * 4 + 0] = __builtin_bit_cast(unsigned short, __float2bfloat16(v.x * invn));
    hb[q * 4 + 1] = __builtin_bit_cast(unsigned short, __float2bfloat16(v.y * invn));
    hb[q * 4 + 2] = __builtin_bit_cast(unsigned short, __float2bfloat16(v.z * invn));
    hb[q * 4 + 3] = __builtin_bit_cast(unsigned short, __float2bfloat16(v.w * invn));
  }
  us8 v0, v1;
#pragma unroll
  for (int i = 0; i < 8; ++i) { v0[i] = hb[i]; v1[i] = hb[i + 8]; }
  *(us8*)(xn + (size_t)(n0 + r) * DD + d0 + cseg) = v0;
  *(us8*)(xn + (size_t)(n0 + r) * DD + d0 + cseg + 8) = v1;
  __syncthreads();
  const int drow = tid >> 2, nseg = (tid & 3) * 16;
  unsigned short hb2[16];
#pragma unroll
  for (int i = 0; i < 16; ++i)
    hb2[i] = __builtin_bit_cast(unsigned short, __float2bfloat16(tile[nseg + i][drow]));
  us8 w0, w1;
#pragma unroll
  for (int i = 0; i < 8; ++i) { w0[i] = hb2[i]; w1[i] = hb2[i + 8]; }
  *(us8*)(xT + (size_t)(d0 + drow) * N + n0 + nseg) = w0;
  *(us8*)(xT + (size_t)(d0 + drow) * N + n0 + nseg + 8) = w1;
}

// ---------------------------------------------------------------------------
// Kernel 3: Gram MFMA (round-12/14 exact structure: single-buffer 32KB,
// 512 threads) with diag-LAST triangular ordering (isolated change).
// ---------------------------------------------------------------------------
#define GBM 128
#define GBK 64

__global__ __launch_bounds__(512, 4) void kern_gram(
    const __hip_bfloat16* __restrict__ xn, const int* __restrict__ codes,
    __hip_bfloat16* __restrict__ Cb, float* __restrict__ col_sum, int N)
{
  __shared__ __hip_bfloat16 lds[2 * GBM * GBK];  // As | Bs, 32 KB total
  __shared__ float csA[GBM], csB[GBM];
  __hip_bfloat16* As = lds;
  __hip_bfloat16* Bs = lds + GBM * GBK;
  const int tid = threadIdx.x;

  // off-diagonal pairs first (bid < T*(T-1)/2), diagonals in the tail
  const int T = N / GBM;
  const int NOFF = T * (T - 1) / 2;
  int ai, bi;
  if ((int)blockIdx.x < NOFF) {
    int idx = blockIdx.x; ai = 0; int rem = T - 1;
    while (idx >= rem) { idx -= rem; ++ai; --rem; }
    bi = ai + 1 + idx;
  } else {
    ai = bi = blockIdx.x - NOFF;
  }
  const bool diag = (ai == bi);
  const int a0 = ai * GBM, b0 = bi * GBM;

  if (tid < GBM) { csA[tid] = 0.f; csB[tid] = 0.f; }

  const int lane = tid & 63, wid = tid >> 6;
  const int wr = wid >> 2, wc = wid & 3;     // 2 x 4 wave grid

  const f32x4 fz = {0.f, 0.f, 0.f, 0.f};
  f32x4 acc[4][2];
#pragma unroll
  for (int m = 0; m < 4; ++m)
#pragma unroll
    for (int n = 0; n < 2; ++n) acc[m][n] = fz;

  int ldsoff[2]; size_t srcA[2], srcB[2];
#pragma unroll
  for (int i = 0; i < 2; ++i) {
    int p = i * 8192 + tid * 16;
    int row = p >> 7, c = (p >> 4) & 7;
    ldsoff[i] = p;
    size_t cc = (size_t)((c ^ (row & 7)) << 4);
    srcA[i] = (size_t)(a0 + row) * (DD * 2) + cc;
    srcB[i] = (size_t)(b0 + row) * (DD * 2) + cc;
  }
  const char* xc = (const char*)xn;

  for (int kc = 0; kc < DD * 2; kc += GBK * 2) {
#pragma unroll
    for (int i = 0; i < 2; ++i) {
      gload16(xc + srcA[i] + kc, (char*)As + ldsoff[i]);
      gload16(xc + srcB[i] + kc, (char*)Bs + ldsoff[i]);
    }
    __syncthreads();
#pragma unroll
    for (int kk = 0; kk < 2; ++kk) {
      const int kb = kk * 64 + (lane >> 4) * 16;
      bf16x8 af[4], bfr[2];
#pragma unroll
      for (int m = 0; m < 4; ++m) {
        int r = wr * 64 + m * 16 + (lane & 15);
        af[m] = *(const bf16x8*)((const char*)As + r * 128 + (kb ^ ((r & 7) << 4)));
      }
#pragma unroll
      for (int n = 0; n < 2; ++n) {
        int r = wc * 32 + n * 16 + (lane & 15);
        bfr[n] = *(const bf16x8*)((const char*)Bs + r * 128 + (kb ^ ((r & 7) << 4)));
      }
#pragma unroll
      for (int m = 0; m < 4; ++m)
#pragma unroll
        for (int n = 0; n < 2; ++n)
          acc[m][n] = __builtin_amdgcn_mfma_f32_16x16x32_bf16(af[m], bfr[n], acc[m][n], 0, 0, 0);
    }
    __syncthreads();   // all LDS reads done -> safe to reuse lds for staging
  }

  // ---- epilogue ----
  char* ldsb = (char*)lds;   // staging: [128 rows][256 B], chunk-XOR swizzled
  const int rq = (lane >> 4) << 2;
  int cb[2];
#pragma unroll
  for (int n = 0; n < 2; ++n) cb[n] = codes[b0 + wc * 32 + n * 16 + (lane & 15)];

  us4 tvs[4][2];             // keep bf16 fragments for the transpose pass
  float colpart[2] = {0.f, 0.f};
  float rowpart[4][4] = {};
#pragma unroll
  for (int m = 0; m < 4; ++m) {
    int ca[4];
#pragma unroll
    for (int j = 0; j < 4; ++j) ca[j] = codes[a0 + wr * 64 + m * 16 + rq + j];
#pragma unroll
    for (int n = 0; n < 2; ++n) {
      const int col = wc * 32 + n * 16 + (lane & 15);
#pragma unroll
      for (int j = 0; j < 4; ++j) {
        int t = ca[j] ^ cb[n];
        t |= t >> 1; t |= t >> 2;
        t &= 0x111111;
        float f = (float)(6 - __popc(t)) * (1.0f / 6.0f);
        float cv = acc[m][n][j] * f;
        colpart[n] += cv;
        rowpart[m][j] += cv;
        __hip_bfloat16 hv = __float2bfloat16(cv);
        tvs[m][n][j] = __builtin_bit_cast(unsigned short, hv);
        const int row = wr * 64 + m * 16 + rq + j;
        const int boff = row * 256 + ((((col >> 3) ^ (row & 7)) << 4) | ((col & 7) << 1));
        *(__hip_bfloat16*)(ldsb + boff) = hv;
      }
    }
  }
#pragma unroll
  for (int n = 0; n < 2; ++n) {
    float v = colpart[n];
    v += __shfl_xor(v, 16);
    v += __shfl_xor(v, 32);
    if (lane < 16) atomicAdd(&csB[wc * 32 + n * 16 + lane], v);
  }
  if (!diag) {
#pragma unroll
    for (int m = 0; m < 4; ++m)
#pragma unroll
      for (int j = 0; j < 4; ++j) {
        float v = rowpart[m][j];
        v += __shfl_xor(v, 1);
        v += __shfl_xor(v, 2);
        v += __shfl_xor(v, 4);
        v += __shfl_xor(v, 8);
        if ((lane & 15) == 0)
          atomicAdd(&csA[wr * 64 + m * 16 + rq + j], v);
      }
  }
  __syncthreads();
  // pass A copy-out: 512 threads, 4 iters cover 128 rows x 256 B
#pragma unroll
  for (int i = 0; i < 4; ++i) {
    const int row = i * 32 + (tid >> 4);
    const int ch = tid & 15;
    us8 v = *(us8*)(ldsb + row * 256 + ((ch ^ (row & 7)) << 4));
    *(us8*)((char*)Cb + ((size_t)(a0 + row) * N + b0) * 2 + (ch << 4)) = v;
  }
  if (!diag) {
    __syncthreads();
#pragma unroll
    for (int m = 0; m < 4; ++m) {
      const int row0 = wr * 64 + m * 16 + rq;
      const int chT = row0 >> 3;
      const int byo = (row0 & 7) << 1;
#pragma unroll
      for (int n = 0; n < 2; ++n) {
        const int col = wc * 32 + n * 16 + (lane & 15);
        *(us4*)(ldsb + col * 256 + (((chT ^ (col & 7)) << 4) | byo)) = tvs[m][n];
      }
    }
    __syncthreads();
#pragma unroll
    for (int i = 0; i < 4; ++i) {
      const int row = i * 32 + (tid >> 4);
      const int ch = tid & 15;
      us8 v = *(us8*)(ldsb + row * 256 + ((ch ^ (row & 7)) << 4));
      *(us8*)((char*)Cb + ((size_t)(b0 + row) * N + a0) * 2 + (ch << 4)) = v;
    }
  }
  if (tid < GBM) {
    atomicAdd(&col_sum[b0 + tid], csB[tid]);
    if (!diag) atomicAdd(&col_sum[a0 + tid], csA[tid]);
  }
}

// ---------------------------------------------------------------------------
// Kernel 4: out2 partials (round-14 exact): 128x128, OSK=4, 512 threads,
// 2-phase stage-early dbuf pipeline, plain f32 partial stores.
// ---------------------------------------------------------------------------
#define OM 128
#define ON 128
#define OK 64
#define OSK 4
#define ONT 16   // K-steps: (4096/4)/64

__global__ __launch_bounds__(512, 4) void kern_out2(
    const __hip_bfloat16* __restrict__ Cb, const __hip_bfloat16* __restrict__ xT,
    float* __restrict__ part, int N)
{
  __shared__ __hip_bfloat16 As[2][OM * OK];   // 2 x 16 KB
  __shared__ __hip_bfloat16 Bs[2][ON * OK];   // 2 x 16 KB
  const int tid = threadIdx.x;
  const int b0 = blockIdx.x * OM;
  const int d0 = blockIdx.y * ON;
  const size_t kbyte0 = (size_t)blockIdx.z * (N / OSK) * 2;
  const int lane = tid & 63, wid = tid >> 6;
  const int wr = wid >> 2, wc = wid & 3;   // 2 x 4 wave grid

  const f32x4 fz = {0.f, 0.f, 0.f, 0.f};
  f32x4 acc[4][2];
#pragma unroll
  for (int m = 0; m < 4; ++m)
#pragma unroll
    for (int n = 0; n < 2; ++n) acc[m][n] = fz;

  int ldso[2]; size_t srcA[2], srcB[2];
#pragma unroll
  for (int i = 0; i < 2; ++i) {
    int p = i * 8192 + tid * 16;
    int row = p >> 7, c = (p >> 4) & 7;
    ldso[i] = p;
    size_t cc = (size_t)((c ^ (row & 7)) << 4);
    srcA[i] = (size_t)(b0 + row) * ((size_t)N * 2) + cc + kbyte0;
    srcB[i] = (size_t)(d0 + row) * ((size_t)N * 2) + cc + kbyte0;
  }
  const char* Ac = (const char*)Cb;
  const char* Bc = (const char*)xT;

#define OSTAGE(t, buf) do { \
    const size_t kc = (size_t)(t) * (OK * 2); \
    _Pragma("unroll") \
    for (int i = 0; i < 2; ++i) { \
      gload16(Ac + srcA[i] + kc, (char*)As[buf] + ldso[i]); \
      gload16(Bc + srcB[i] + kc, (char*)Bs[buf] + ldso[i]); \
    } } while (0)

  OSTAGE(0, 0);
  asm volatile("s_waitcnt vmcnt(0)" ::: "memory");
  __builtin_amdgcn_s_barrier();

  for (int t = 0; t < ONT; ++t) {
    const int cur = t & 1;
    if (t + 1 < ONT) OSTAGE(t + 1, cur ^ 1);   // overlap with compute below
    const char* Ab = (const char*)As[cur];
    const char* Bb = (const char*)Bs[cur];
#pragma unroll
    for (int kk = 0; kk < 2; ++kk) {
      const int kb = kk * 64 + (lane >> 4) * 16;
      bf16x8 af[4], bfr[2];
#pragma unroll
      for (int m = 0; m < 4; ++m) {
        int r = wr * 64 + m * 16 + (lane & 15);
        af[m] = *(const bf16x8*)(Ab + r * 128 + (kb ^ ((r & 7) << 4)));
      }
#pragma unroll
      for (int n = 0; n < 2; ++n) {
        int r = wc * 32 + n * 16 + (lane & 15);
        bfr[n] = *(const bf16x8*)(Bb + r * 128 + (kb ^ ((r & 7) << 4)));
      }
#pragma unroll
      for (int m = 0; m < 4; ++m)
#pragma unroll
        for (int n = 0; n < 2; ++n)
          acc[m][n] = __builtin_amdgcn_mfma_f32_16x16x32_bf16(af[m], bfr[n], acc[m][n], 0, 0, 0);
    }
    asm volatile("s_waitcnt vmcnt(0)" ::: "memory");
    __builtin_amdgcn_s_barrier();
  }
#undef OSTAGE

  float* pz = part + (size_t)blockIdx.z * N * DD;
#pragma unroll
  for (int m = 0; m < 4; ++m)
#pragma unroll
    for (int j = 0; j < 4; ++j) {
      int b = b0 + wr * 64 + m * 16 + ((lane >> 4) << 2) + j;
#pragma unroll
      for (int n = 0; n < 2; ++n) {
        int d = d0 + wc * 32 + n * 16 + (lane & 15);
        pz[(size_t)b * DD + d] = acc[m][n][j];
      }
    }
}

// ---------------------------------------------------------------------------
// Kernel 5: finish. One block per row n; sums `osk` partial slices.
// ---------------------------------------------------------------------------
__global__ __launch_bounds__(256) void kern_finish(
    const float* __restrict__ x, const float* __restrict__ col_sum,
    const float* __restrict__ part, float* __restrict__ out, int N, int osk)
{
  const int n = blockIdx.x;
  const int tid = threadIdx.x;
  const float invN = 1.0f / (float)N;
  if (tid < 128) {
    const float s = col_sum[n] * invN;
    float4 v = ((const float4*)(x + (size_t)n * DD))[tid];
    v.x *= s; v.y *= s; v.z *= s; v.w *= s;
    ((float4*)(out + (size_t)n * (2 * DD)))[tid] = v;
  } else {
    const int d4 = tid - 128;
    const size_t stride = (size_t)N * DD;
    float4 r = {0.f, 0.f, 0.f, 0.f};
    for (int z = 0; z < osk; ++z) {
      float4 p = *((const float4*)(part + (size_t)z * stride + (size_t)n * DD) + d4);
      r.x += p.x; r.y += p.y; r.z += p.z; r.w += p.w;
    }
    r.x *= invN; r.y *= invN; r.z *= invN; r.w *= invN;
    ((float4*)(out + (size_t)n * (2 * DD) + DD))[d4] = r;
  }
}

extern "C" void kernel_launch(void* const* d_in, const int* in_sizes, int n_in,
                              void* d_out, int out_size, void* d_ws, size_t ws_size,
                              hipStream_t stream) {
  const float* x = (const float*)d_in[0];
  const float* H = (const float*)d_in[1];
  float* out = (float*)d_out;
  const int N = in_sizes[0] / DD;  // 4096

  char* ws = (char*)d_ws;
  __hip_bfloat16* Cb   = (__hip_bfloat16*)ws;                       // N*N bf16 (32 MB)
  __hip_bfloat16* xn16 = (__hip_bfloat16*)(ws + (size_t)N * N * 2); // N*DD bf16 (4 MB)
  __hip_bfloat16* xT16 = xn16 + (size_t)N * DD;                     // DD*N bf16 (4 MB)
  float* col_sum  = (float*)(xT16 + (size_t)N * DD);                // N f32
  float* inv_norm = col_sum + N;                                    // N f32
  int*   codes    = (int*)(inv_norm + N);                           // N int
  float* part     = (float*)(codes + N);                            // OSK*N*DD f32

  kern_wmax<<<N / 4, 256, 0, stream>>>(x, H, codes, inv_norm, col_sum);
  kern_prep<<<dim3(N / 64, DD / 64), 256, 0, stream>>>(x, inv_norm, xn16, xT16, N);
  const int T = N / GBM;
  kern_gram<<<T * (T + 1) / 2, 512, 0, stream>>>(xn16, codes, Cb, col_sum, N);
  kern_out2<<<dim3(N / OM, DD / ON, OSK), 512, 0, stream>>>(Cb, xT16, part, N);
  kern_finish<<<N, 256, 0, stream>>>(x, col_sum, part, out, N, OSK);
}

// Round 17
// 83.120 us; speedup vs baseline: 1.1088x; 1.0027x over previous
//
#include <hip/hip_runtime.h>
#include <hip/hip_bf16.h>

#define DD 512      // feature dim
#define NTOP 10     // topic_e
#define NTK 6       // num_topics
#define NPAIR 60    // NTOP*NTK

typedef float f32x4 __attribute__((ext_vector_type(4)));
typedef short bf16x8 __attribute__((ext_vector_type(8)));
typedef unsigned short us8 __attribute__((ext_vector_type(8)));
typedef unsigned short us4 __attribute__((ext_vector_type(4)));

__device__ __forceinline__ void gload16(const void* g, void* l) {
  __builtin_amdgcn_global_load_lds(
      (const __attribute__((address_space(1))) unsigned int*)g,
      (__attribute__((address_space(3))) unsigned int*)l, 16, 0, 0);
}

// ---------------------------------------------------------------------------
// Kernel 1: per-row argmax (packed nibble code) + inverse norm + col_sum=0.
// ---------------------------------------------------------------------------
__global__ __launch_bounds__(256) void kern_wmax(
    const float* __restrict__ x, const float* __restrict__ H,
    int* __restrict__ codes, float* __restrict__ inv_norm,
    float* __restrict__ col_sum)
{
  __shared__ float xs[4][DD];
  __shared__ float w[4][NPAIR];
  const int wv = threadIdx.x >> 6, lane = threadIdx.x & 63;
  const int n = blockIdx.x * 4 + wv;
  const float* xr = x + (size_t)n * DD;
  float ss = 0.f;
#pragma unroll
  for (int j = 0; j < 2; ++j) {
    float4 v = *(const float4*)(xr + j * 256 + lane * 4);
    *(float4*)&xs[wv][j * 256 + lane * 4] = v;
    ss = fmaf(v.x, v.x, fmaf(v.y, v.y, fmaf(v.z, v.z, fmaf(v.w, v.w, ss))));
  }
#pragma unroll
  for (int off = 32; off; off >>= 1) ss += __shfl_xor(ss, off);
  if (lane == 0) inv_norm[n] = 1.0f / fmaxf(sqrtf(ss), 1e-8f);
  __syncthreads();
  if (lane < NPAIR) {
    float acc = 0.f;
#pragma unroll 8
    for (int d = 0; d < DD; ++d) acc = fmaf(xs[wv][d], H[d * NPAIR + lane], acc);
    w[wv][lane] = acc;
  }
  __syncthreads();
  int myc = 0;
  if (lane < NTK) {
    float best = w[wv][lane];
    int bi = 0;
#pragma unroll
    for (int t = 1; t < NTOP; ++t) {
      float v = w[wv][t * NTK + lane];
      if (v > best) { best = v; bi = t; }  // strict > == jnp.argmax first-index tie rule
    }
    myc = bi << (4 * lane);
  }
#pragma unroll
  for (int off = 1; off <= 4; off <<= 1) myc |= __shfl_xor(myc, off);
  if (lane == 0) { codes[n] = myc; col_sum[n] = 0.f; }
}

// ---------------------------------------------------------------------------
// Kernel 2: xn = bf16(x * inv_norm) row-major; xT = bf16(x)^T  (D x N)
// ---------------------------------------------------------------------------
__global__ __launch_bounds__(256) void kern_prep(
    const float* __restrict__ x, const float* __restrict__ inv_norm,
    __hip_bfloat16* __restrict__ xn, __hip_bfloat16* __restrict__ xT, int N)
{
  __shared__ float tile[64][65];
  const int n0 = blockIdx.x * 64, d0 = blockIdx.y * 64;
  const int tid = threadIdx.x;
  const int r = tid >> 2, cseg = (tid & 3) * 16;
  const float* src = x + (size_t)(n0 + r) * DD + d0 + cseg;
  const float invn = inv_norm[n0 + r];
  unsigned short hb[16];
#pragma unroll
  for (int q = 0; q < 4; ++q) {
    float4 v = *(const float4*)(src + q * 4);
    tile[r][cseg + q * 4 + 0] = v.x; tile[r][cseg + q * 4 + 1] = v.y;
    tile[r][cseg + q * 4 + 2] = v.z; tile[r][cseg + q * 4 + 3] = v.w;
    hb[q * 4 + 0] = __builtin_bit_cast(unsigned short, __float2bfloat16(v.x * invn));
    hb[q * 4 + 1] = __builtin_bit_cast(unsigned short, __float2bfloat16(v.y * invn));
    hb[q * 4 + 2] = __builtin_bit_cast(unsigned short, __float2bfloat16(v.z * invn));
    hb[q * 4 + 3] = __builtin_bit_cast(unsigned short, __float2bfloat16(v.w * invn));
  }
  us8 v0, v1;
#pragma unroll
  for (int i = 0; i < 8; ++i) { v0[i] = hb[i]; v1[i] = hb[i + 8]; }
  *(us8*)(xn + (size_t)(n0 + r) * DD + d0 + cseg) = v0;
  *(us8*)(xn + (size_t)(n0 + r) * DD + d0 + cseg + 8) = v1;
  __syncthreads();
  const int drow = tid >> 2, nseg = (tid & 3) * 16;
  unsigned short hb2[16];
#pragma unroll
  for (int i = 0; i < 16; ++i)
    hb2[i] = __builtin_bit_cast(unsigned short, __float2bfloat16(tile[nseg + i][drow]));
  us8 w0, w1;
#pragma unroll
  for (int i = 0; i < 8; ++i) { w0[i] = hb2[i]; w1[i] = hb2[i + 8]; }
  *(us8*)(xT + (size_t)(d0 + drow) * N + n0 + nseg) = w0;
  *(us8*)(xT + (size_t)(d0 + drow) * N + n0 + nseg + 8) = w1;
}

// ---------------------------------------------------------------------------
// Kernel 3: Gram MFMA (round-16 exact): single-buffer 32KB, 512 threads,
// diag-LAST triangular ordering.
// ---------------------------------------------------------------------------
#define GBM 128
#define GBK 64

__global__ __launch_bounds__(512, 4) void kern_gram(
    const __hip_bfloat16* __restrict__ xn, const int* __restrict__ codes,
    __hip_bfloat16* __restrict__ Cb, float* __restrict__ col_sum, int N)
{
  __shared__ __hip_bfloat16 lds[2 * GBM * GBK];  // As | Bs, 32 KB total
  __shared__ float csA[GBM], csB[GBM];
  __hip_bfloat16* As = lds;
  __hip_bfloat16* Bs = lds + GBM * GBK;
  const int tid = threadIdx.x;

  // off-diagonal pairs first (bid < T*(T-1)/2), diagonals in the tail
  const int T = N / GBM;
  const int NOFF = T * (T - 1) / 2;
  int ai, bi;
  if ((int)blockIdx.x < NOFF) {
    int idx = blockIdx.x; ai = 0; int rem = T - 1;
    while (idx >= rem) { idx -= rem; ++ai; --rem; }
    bi = ai + 1 + idx;
  } else {
    ai = bi = blockIdx.x - NOFF;
  }
  const bool diag = (ai == bi);
  const int a0 = ai * GBM, b0 = bi * GBM;

  if (tid < GBM) { csA[tid] = 0.f; csB[tid] = 0.f; }

  const int lane = tid & 63, wid = tid >> 6;
  const int wr = wid >> 2, wc = wid & 3;     // 2 x 4 wave grid

  const f32x4 fz = {0.f, 0.f, 0.f, 0.f};
  f32x4 acc[4][2];
#pragma unroll
  for (int m = 0; m < 4; ++m)
#pragma unroll
    for (int n = 0; n < 2; ++n) acc[m][n] = fz;

  int ldsoff[2]; size_t srcA[2], srcB[2];
#pragma unroll
  for (int i = 0; i < 2; ++i) {
    int p = i * 8192 + tid * 16;
    int row = p >> 7, c = (p >> 4) & 7;
    ldsoff[i] = p;
    size_t cc = (size_t)((c ^ (row & 7)) << 4);
    srcA[i] = (size_t)(a0 + row) * (DD * 2) + cc;
    srcB[i] = (size_t)(b0 + row) * (DD * 2) + cc;
  }
  const char* xc = (const char*)xn;

  for (int kc = 0; kc < DD * 2; kc += GBK * 2) {
#pragma unroll
    for (int i = 0; i < 2; ++i) {
      gload16(xc + srcA[i] + kc, (char*)As + ldsoff[i]);
      gload16(xc + srcB[i] + kc, (char*)Bs + ldsoff[i]);
    }
    __syncthreads();
#pragma unroll
    for (int kk = 0; kk < 2; ++kk) {
      const int kb = kk * 64 + (lane >> 4) * 16;
      bf16x8 af[4], bfr[2];
#pragma unroll
      for (int m = 0; m < 4; ++m) {
        int r = wr * 64 + m * 16 + (lane & 15);
        af[m] = *(const bf16x8*)((const char*)As + r * 128 + (kb ^ ((r & 7) << 4)));
      }
#pragma unroll
      for (int n = 0; n < 2; ++n) {
        int r = wc * 32 + n * 16 + (lane & 15);
        bfr[n] = *(const bf16x8*)((const char*)Bs + r * 128 + (kb ^ ((r & 7) << 4)));
      }
#pragma unroll
      for (int m = 0; m < 4; ++m)
#pragma unroll
        for (int n = 0; n < 2; ++n)
          acc[m][n] = __builtin_amdgcn_mfma_f32_16x16x32_bf16(af[m], bfr[n], acc[m][n], 0, 0, 0);
    }
    __syncthreads();   // all LDS reads done -> safe to reuse lds for staging
  }

  // ---- epilogue ----
  char* ldsb = (char*)lds;   // staging: [128 rows][256 B], chunk-XOR swizzled
  const int rq = (lane >> 4) << 2;
  int cb[2];
#pragma unroll
  for (int n = 0; n < 2; ++n) cb[n] = codes[b0 + wc * 32 + n * 16 + (lane & 15)];

  us4 tvs[4][2];             // keep bf16 fragments for the transpose pass
  float colpart[2] = {0.f, 0.f};
  float rowpart[4][4] = {};
#pragma unroll
  for (int m = 0; m < 4; ++m) {
    int ca[4];
#pragma unroll
    for (int j = 0; j < 4; ++j) ca[j] = codes[a0 + wr * 64 + m * 16 + rq + j];
#pragma unroll
    for (int n = 0; n < 2; ++n) {
      const int col = wc * 32 + n * 16 + (lane & 15);
#pragma unroll
      for (int j = 0; j < 4; ++j) {
        int t = ca[j] ^ cb[n];
        t |= t >> 1; t |= t >> 2;
        t &= 0x111111;
        float f = (float)(6 - __popc(t)) * (1.0f / 6.0f);
        float cv = acc[m][n][j] * f;
        colpart[n] += cv;
        rowpart[m][j] += cv;
        __hip_bfloat16 hv = __float2bfloat16(cv);
        tvs[m][n][j] = __builtin_bit_cast(unsigned short, hv);
        const int row = wr * 64 + m * 16 + rq + j;
        const int boff = row * 256 + ((((col >> 3) ^ (row & 7)) << 4) | ((col & 7) << 1));
        *(__hip_bfloat16*)(ldsb + boff) = hv;
      }
    }
  }
#pragma unroll
  for (int n = 0; n < 2; ++n) {
    float v = colpart[n];
    v += __shfl_xor(v, 16);
    v += __shfl_xor(v, 32);
    if (lane < 16) atomicAdd(&csB[wc * 32 + n * 16 + lane], v);
  }
  if (!diag) {
#pragma unroll
    for (int m = 0; m < 4; ++m)
#pragma unroll
      for (int j = 0; j < 4; ++j) {
        float v = rowpart[m][j];
        v += __shfl_xor(v, 1);
        v += __shfl_xor(v, 2);
        v += __shfl_xor(v, 4);
        v += __shfl_xor(v, 8);
        if ((lane & 15) == 0)
          atomicAdd(&csA[wr * 64 + m * 16 + rq + j], v);
      }
  }
  __syncthreads();
  // pass A copy-out: 512 threads, 4 iters cover 128 rows x 256 B
#pragma unroll
  for (int i = 0; i < 4; ++i) {
    const int row = i * 32 + (tid >> 4);
    const int ch = tid & 15;
    us8 v = *(us8*)(ldsb + row * 256 + ((ch ^ (row & 7)) << 4));
    *(us8*)((char*)Cb + ((size_t)(a0 + row) * N + b0) * 2 + (ch << 4)) = v;
  }
  if (!diag) {
    __syncthreads();
#pragma unroll
    for (int m = 0; m < 4; ++m) {
      const int row0 = wr * 64 + m * 16 + rq;
      const int chT = row0 >> 3;
      const int byo = (row0 & 7) << 1;
#pragma unroll
      for (int n = 0; n < 2; ++n) {
        const int col = wc * 32 + n * 16 + (lane & 15);
        *(us4*)(ldsb + col * 256 + (((chT ^ (col & 7)) << 4) | byo)) = tvs[m][n];
      }
    }
    __syncthreads();
#pragma unroll
    for (int i = 0; i < 4; ++i) {
      const int row = i * 32 + (tid >> 4);
      const int ch = tid & 15;
      us8 v = *(us8*)(ldsb + row * 256 + ((ch ^ (row & 7)) << 4));
      *(us8*)((char*)Cb + ((size_t)(b0 + row) * N + a0) * 2 + (ch << 4)) = v;
    }
  }
  if (tid < GBM) {
    atomicAdd(&col_sum[b0 + tid], csB[tid]);
    if (!diag) atomicAdd(&col_sum[a0 + tid], csA[tid]);
  }
}

// ---------------------------------------------------------------------------
// Kernel 4: out2 partials (round-14 structure) with XCD-grouped 1-D grid:
// id = xcd + 8*(by + 4*q), bx = xcd + 8*(q&3), bz = q>>2. The 4 by-variants
// of each (bx,bz) C-panel get ids {k,k+8,k+16,k+24} -> same XCD, consecutive
// rounds -> C panel stays L2-hot across its 4 uses.
// ---------------------------------------------------------------------------
#define OM 128
#define ON 128
#define OK 64
#define OSK 4
#define ONT 16   // K-steps: (4096/4)/64

__global__ __launch_bounds__(512, 4) void kern_out2(
    const __hip_bfloat16* __restrict__ Cb, const __hip_bfloat16* __restrict__ xT,
    float* __restrict__ part, int N)
{
  __shared__ __hip_bfloat16 As[2][OM * OK];   // 2 x 16 KB
  __shared__ __hip_bfloat16 Bs[2][ON * OK];   // 2 x 16 KB
  const int tid = threadIdx.x;
  // XCD-grouped decode
  const int id = blockIdx.x;
  const int xcd = id & 7;
  const int rdec = id >> 3;
  const int by = rdec & 3;
  const int q = rdec >> 2;                 // 0..15
  const int bx = xcd + ((q & 3) << 3);     // 0..31
  const int bz = q >> 2;                   // 0..3
  const int b0 = bx * OM;
  const int d0 = by * ON;
  const size_t kbyte0 = (size_t)bz * (N / OSK) * 2;
  const int lane = tid & 63, wid = tid >> 6;
  const int wr = wid >> 2, wc = wid & 3;   // 2 x 4 wave grid

  const f32x4 fz = {0.f, 0.f, 0.f, 0.f};
  f32x4 acc[4][2];
#pragma unroll
  for (int m = 0; m < 4; ++m)
#pragma unroll
    for (int n = 0; n < 2; ++n) acc[m][n] = fz;

  int ldso[2]; size_t srcA[2], srcB[2];
#pragma unroll
  for (int i = 0; i < 2; ++i) {
    int p = i * 8192 + tid * 16;
    int row = p >> 7, c = (p >> 4) & 7;
    ldso[i] = p;
    size_t cc = (size_t)((c ^ (row & 7)) << 4);
    srcA[i] = (size_t)(b0 + row) * ((size_t)N * 2) + cc + kbyte0;
    srcB[i] = (size_t)(d0 + row) * ((size_t)N * 2) + cc + kbyte0;
  }
  const char* Ac = (const char*)Cb;
  const char* Bc = (const char*)xT;

#define OSTAGE(t, buf) do { \
    const size_t kc = (size_t)(t) * (OK * 2); \
    _Pragma("unroll") \
    for (int i = 0; i < 2; ++i) { \
      gload16(Ac + srcA[i] + kc, (char*)As[buf] + ldso[i]); \
      gload16(Bc + srcB[i] + kc, (char*)Bs[buf] + ldso[i]); \
    } } while (0)

  OSTAGE(0, 0);
  asm volatile("s_waitcnt vmcnt(0)" ::: "memory");
  __builtin_amdgcn_s_barrier();

  for (int t = 0; t < ONT; ++t) {
    const int cur = t & 1;
    if (t + 1 < ONT) OSTAGE(t + 1, cur ^ 1);   // overlap with compute below
    const char* Ab = (const char*)As[cur];
    const char* Bb = (const char*)Bs[cur];
#pragma unroll
    for (int kk = 0; kk < 2; ++kk) {
      const int kb = kk * 64 + (lane >> 4) * 16;
      bf16x8 af[4], bfr[2];
#pragma unroll
      for (int m = 0; m < 4; ++m) {
        int r = wr * 64 + m * 16 + (lane & 15);
        af[m] = *(const bf16x8*)(Ab + r * 128 + (kb ^ ((r & 7) << 4)));
      }
#pragma unroll
      for (int n = 0; n < 2; ++n) {
        int r = wc * 32 + n * 16 + (lane & 15);
        bfr[n] = *(const bf16x8*)(Bb + r * 128 + (kb ^ ((r & 7) << 4)));
      }
#pragma unroll
      for (int m = 0; m < 4; ++m)
#pragma unroll
        for (int n = 0; n < 2; ++n)
          acc[m][n] = __builtin_amdgcn_mfma_f32_16x16x32_bf16(af[m], bfr[n], acc[m][n], 0, 0, 0);
    }
    asm volatile("s_waitcnt vmcnt(0)" ::: "memory");
    __builtin_amdgcn_s_barrier();
  }
#undef OSTAGE

  float* pz = part + (size_t)bz * N * DD;
#pragma unroll
  for (int m = 0; m < 4; ++m)
#pragma unroll
    for (int j = 0; j < 4; ++j) {
      int b = b0 + wr * 64 + m * 16 + ((lane >> 4) << 2) + j;
#pragma unroll
      for (int n = 0; n < 2; ++n) {
        int d = d0 + wc * 32 + n * 16 + (lane & 15);
        pz[(size_t)b * DD + d] = acc[m][n][j];
      }
    }
}

// ---------------------------------------------------------------------------
// Kernel 5: finish. One block per row n; sums `osk` partial slices.
// ---------------------------------------------------------------------------
__global__ __launch_bounds__(256) void kern_finish(
    const float* __restrict__ x, const float* __restrict__ col_sum,
    const float* __restrict__ part, float* __restrict__ out, int N, int osk)
{
  const int n = blockIdx.x;
  const int tid = threadIdx.x;
  const float invN = 1.0f / (float)N;
  if (tid < 128) {
    const float s = col_sum[n] * invN;
    float4 v = ((const float4*)(x + (size_t)n * DD))[tid];
    v.x *= s; v.y *= s; v.z *= s; v.w *= s;
    ((float4*)(out + (size_t)n * (2 * DD)))[tid] = v;
  } else {
    const int d4 = tid - 128;
    const size_t stride = (size_t)N * DD;
    float4 r = {0.f, 0.f, 0.f, 0.f};
    for (int z = 0; z < osk; ++z) {
      float4 p = *((const float4*)(part + (size_t)z * stride + (size_t)n * DD) + d4);
      r.x += p.x; r.y += p.y; r.z += p.z; r.w += p.w;
    }
    r.x *= invN; r.y *= invN; r.z *= invN; r.w *= invN;
    ((float4*)(out + (size_t)n * (2 * DD) + DD))[d4] = r;
  }
}

extern "C" void kernel_launch(void* const* d_in, const int* in_sizes, int n_in,
                              void* d_out, int out_size, void* d_ws, size_t ws_size,
                              hipStream_t stream) {
  const float* x = (const float*)d_in[0];
  const float* H = (const float*)d_in[1];
  float* out = (float*)d_out;
  const int N = in_sizes[0] / DD;  // 4096

  char* ws = (char*)d_ws;
  __hip_bfloat16* Cb   = (__hip_bfloat16*)ws;                       // N*N bf16 (32 MB)
  __hip_bfloat16* xn16 = (__hip_bfloat16*)(ws + (size_t)N * N * 2); // N*DD bf16 (4 MB)
  __hip_bfloat16* xT16 = xn16 + (size_t)N * DD;                     // DD*N bf16 (4 MB)
  float* col_sum  = (float*)(xT16 + (size_t)N * DD);                // N f32
  float* inv_norm = col_sum + N;                                    // N f32
  int*   codes    = (int*)(inv_norm + N);                           // N int
  float* part     = (float*)(codes + N);                            // OSK*N*DD f32

  kern_wmax<<<N / 4, 256, 0, stream>>>(x, H, codes, inv_norm, col_sum);
  kern_prep<<<dim3(N / 64, DD / 64), 256, 0, stream>>>(x, inv_norm, xn16, xT16, N);
  const int T = N / GBM;
  kern_gram<<<T * (T + 1) / 2, 512, 0, stream>>>(xn16, codes, Cb, col_sum, N);
  kern_out2<<<(N / OM) * (DD / ON) * OSK, 512, 0, stream>>>(Cb, xT16, part, N);
  kern_finish<<<N, 256, 0, stream>>>(x, col_sum, part, out, N, OSK);
}